// Round 1
// baseline (336.108 us; speedup 1.0000x reference)
//
#include <hip/hip_runtime.h>

typedef __attribute__((ext_vector_type(8))) __bf16 bf16x8;
typedef __attribute__((ext_vector_type(4))) float f32x4;
typedef __attribute__((ext_vector_type(4))) unsigned int u32x4;

#define NBATCH 4
#define NV 100000
#define NE 400000
#define DIN 256
#define HID 128
#define DOUT 64

// LDS layout (bytes)
#define W1T_OFF 0            // 128 rows x 512B (bf16, swizzled)
#define W2T_OFF 65536        // 64 rows x 256B (bf16, swizzled)
#define HB_OFF  81920        // 8 waves x 8192B (32 rows x 256B, swizzled)
#define B1_OFF  147456       // 512B f32
#define B2_OFF  147968       // 256B f32
#define LDS_SIZE 148224

__device__ inline unsigned short f2b_rne(float f) {
    unsigned u = __builtin_bit_cast(unsigned, f);
    return (unsigned short)((u + 0x7fffu + ((u >> 16) & 1u)) >> 16);
}

__device__ inline bf16x8 pack8(f32x4 a, f32x4 b) {
    unsigned r0, r1, r2, r3;
    asm("v_cvt_pk_bf16_f32 %0, %1, %2" : "=v"(r0) : "v"(a[0]), "v"(a[1]));
    asm("v_cvt_pk_bf16_f32 %0, %1, %2" : "=v"(r1) : "v"(a[2]), "v"(a[3]));
    asm("v_cvt_pk_bf16_f32 %0, %1, %2" : "=v"(r2) : "v"(b[0]), "v"(b[1]));
    asm("v_cvt_pk_bf16_f32 %0, %1, %2" : "=v"(r3) : "v"(b[2]), "v"(b[3]));
    u32x4 u = {r0, r1, r2, r3};
    return __builtin_bit_cast(bf16x8, u);
}

__device__ inline bf16x8 load8(const float* p) {
    f32x4 x = *(const f32x4*)p;
    f32x4 y = *(const f32x4*)(p + 4);
    return pack8(x, y);
}

__global__ __launch_bounds__(512, 2) void edgeblock_kernel(
    const float* __restrict__ vdata, const float* __restrict__ edata,
    const float* __restrict__ cdata, const float* __restrict__ W1,
    const float* __restrict__ b1, const float* __restrict__ W2,
    const float* __restrict__ b2, const int* __restrict__ snd,
    const int* __restrict__ rcv, float* __restrict__ out)
{
    __shared__ __align__(16) unsigned char lds[LDS_SIZE];
    const int tid = threadIdx.x;
    const int lane = tid & 63;
    const int w = tid >> 6;        // wave 0..7
    const int l15 = lane & 15;
    const int lg = lane >> 4;      // 0..3

    const int b   = blockIdx.x >> 6;   // batch 0..3
    const int blk = blockIdx.x & 63;   // block-in-batch 0..63

    // ---- one-time init: W1^T, W2^T (bf16, swizzled), biases into LDS ----
    for (int i = tid; i < DIN * HID; i += 512) {
        int k = i >> 7, n = i & 127;
        unsigned short h = f2b_rne(W1[i]);
        *(unsigned short*)(lds + W1T_OFF + n * 512 + ((k * 2) ^ ((n & 7) << 4))) = h;
    }
    for (int i = tid; i < HID * DOUT; i += 512) {
        int k = i >> 6, n = i & 63;
        unsigned short h = f2b_rne(W2[i]);
        *(unsigned short*)(lds + W2T_OFF + n * 256 + ((k * 2) ^ ((n & 7) << 4))) = h;
    }
    if (tid < HID)  *(float*)(lds + B1_OFF + tid * 4) = b1[tid];
    if (tid < DOUT) *(float*)(lds + B2_OFF + tid * 4) = b2[tid];
    __syncthreads();

    // per-wave invariants
    float b1v[8], b2v[4];
#pragma unroll
    for (int n = 0; n < 8; ++n) b1v[n] = *(const float*)(lds + B1_OFF + (n * 16 + l15) * 4);
#pragma unroll
    for (int n = 0; n < 4; ++n) b2v[n] = *(const float*)(lds + B2_OFF + (n * 16 + l15) * 4);

    const float* cd = cdata + b * 64;
    bf16x8 cfr0 = load8(cd + lg * 8);
    bf16x8 cfr1 = load8(cd + 32 + lg * 8);

    const size_t bE = (size_t)b * NE;
    const float* ed_b = edata + bE * 64;
    const float* vd_b = vdata + (size_t)b * NV * 64;
    const int* snd_b = snd + bE;
    const int* rcv_b = rcv + bE;
    float* out_b = out + bE * 64;
    unsigned char* hb = lds + HB_OFF + w * 8192;

    const int n_tiles = NE / 32;  // 12500
    for (int t = blk * 8 + w; t < n_tiles; t += 512) {
        const int e0 = t * 32;

        int sid0 = snd_b[e0 + l15], sid1 = snd_b[e0 + 16 + l15];
        int rid0 = rcv_b[e0 + l15], rid1 = rcv_b[e0 + 16 + l15];

        // ---- gather A fragments: etin[32 edges][256] as bf16 frags ----
        bf16x8 a[2][8];
        {
            const float* erow0 = ed_b + (size_t)(e0 + l15) * 64;
            const float* erow1 = ed_b + (size_t)(e0 + 16 + l15) * 64;
            const float* srow0 = vd_b + (size_t)sid0 * 64;
            const float* srow1 = vd_b + (size_t)sid1 * 64;
            const float* rrow0 = vd_b + (size_t)rid0 * 64;
            const float* rrow1 = vd_b + (size_t)rid1 * 64;
            const int c0 = lg * 8;
            a[0][0] = load8(erow0 + c0);      a[0][1] = load8(erow0 + 32 + c0);
            a[0][2] = load8(srow0 + c0);      a[0][3] = load8(srow0 + 32 + c0);
            a[0][4] = load8(rrow0 + c0);      a[0][5] = load8(rrow0 + 32 + c0);
            a[0][6] = cfr0;                   a[0][7] = cfr1;
            a[1][0] = load8(erow1 + c0);      a[1][1] = load8(erow1 + 32 + c0);
            a[1][2] = load8(srow1 + c0);      a[1][3] = load8(srow1 + 32 + c0);
            a[1][4] = load8(rrow1 + c0);      a[1][5] = load8(rrow1 + 32 + c0);
            a[1][6] = cfr0;                   a[1][7] = cfr1;
        }

        // ---- layer 1: [32x256] @ [256x128] ----
        f32x4 acc[2][8];
#pragma unroll
        for (int mt = 0; mt < 2; ++mt)
#pragma unroll
            for (int n = 0; n < 8; ++n) { f32x4 z = {0.f, 0.f, 0.f, 0.f}; acc[mt][n] = z; }

#pragma unroll
        for (int n = 0; n < 8; ++n) {
            const int row = n * 16 + l15;
            const unsigned char* wrow = lds + W1T_OFF + row * 512;
            const int swz = (row & 7) << 4;
#pragma unroll
            for (int kk = 0; kk < 8; ++kk) {
                bf16x8 bf = *(const bf16x8*)(wrow + ((kk * 64 + lg * 16) ^ swz));
                acc[0][n] = __builtin_amdgcn_mfma_f32_16x16x32_bf16(a[0][kk], bf, acc[0][n], 0, 0, 0);
                acc[1][n] = __builtin_amdgcn_mfma_f32_16x16x32_bf16(a[1][kk], bf, acc[1][n], 0, 0, 0);
            }
        }

        // ---- bias + relu + h -> LDS (bf16, swizzled) ----
#pragma unroll
        for (int mt = 0; mt < 2; ++mt)
#pragma unroll
            for (int n = 0; n < 8; ++n)
#pragma unroll
                for (int r = 0; r < 4; ++r) {
                    int row = mt * 16 + lg * 4 + r;
                    int col = n * 16 + l15;
                    float hv = fmaxf(acc[mt][n][r] + b1v[n], 0.f);
                    *(unsigned short*)(hb + row * 256 + ((col * 2) ^ ((row & 7) << 4))) = f2b_rne(hv);
                }

        // ---- layer 2: [32x128] @ [128x64] ----
        bf16x8 ha[2][4];
#pragma unroll
        for (int mt = 0; mt < 2; ++mt) {
            const int row = mt * 16 + l15;
            const int swz = (row & 7) << 4;
#pragma unroll
            for (int kk = 0; kk < 4; ++kk)
                ha[mt][kk] = *(const bf16x8*)(hb + row * 256 + ((kk * 64 + lg * 16) ^ swz));
        }

        f32x4 acc2[2][4];
#pragma unroll
        for (int mt = 0; mt < 2; ++mt)
#pragma unroll
            for (int nt = 0; nt < 4; ++nt) { f32x4 z = {0.f, 0.f, 0.f, 0.f}; acc2[mt][nt] = z; }

#pragma unroll
        for (int nt = 0; nt < 4; ++nt) {
            const int rw = nt * 16 + l15;
            const unsigned char* wrow = lds + W2T_OFF + rw * 256;
            const int swz = (rw & 7) << 4;
#pragma unroll
            for (int kk = 0; kk < 4; ++kk) {
                bf16x8 bf = *(const bf16x8*)(wrow + ((kk * 64 + lg * 16) ^ swz));
                acc2[0][nt] = __builtin_amdgcn_mfma_f32_16x16x32_bf16(ha[0][kk], bf, acc2[0][nt], 0, 0, 0);
                acc2[1][nt] = __builtin_amdgcn_mfma_f32_16x16x32_bf16(ha[1][kk], bf, acc2[1][nt], 0, 0, 0);
            }
        }

        // ---- epilogue: + b2, store f32 ----
#pragma unroll
        for (int mt = 0; mt < 2; ++mt)
#pragma unroll
            for (int nt = 0; nt < 4; ++nt)
#pragma unroll
                for (int r = 0; r < 4; ++r) {
                    int e = e0 + mt * 16 + lg * 4 + r;
                    out_b[(size_t)e * 64 + nt * 16 + l15] = acc2[mt][nt][r] + b2v[nt];
                }
    }
}

extern "C" void kernel_launch(void* const* d_in, const int* in_sizes, int n_in,
                              void* d_out, int out_size, void* d_ws, size_t ws_size,
                              hipStream_t stream) {
    const float* vdata = (const float*)d_in[0];
    const float* edata = (const float*)d_in[1];
    const float* cdata = (const float*)d_in[2];
    const float* W1    = (const float*)d_in[3];
    const float* b1    = (const float*)d_in[4];
    const float* W2    = (const float*)d_in[5];
    const float* b2    = (const float*)d_in[6];
    const int*   snd   = (const int*)d_in[7];
    const int*   rcv   = (const int*)d_in[8];
    float* out = (float*)d_out;

    edgeblock_kernel<<<dim3(256), dim3(512), 0, stream>>>(
        vdata, edata, cdata, W1, b1, W2, b2, snd, rcv, out);
}